// Round 1
// baseline (650.142 us; speedup 1.0000x reference)
//
#include <hip/hip_runtime.h>
#include <hip/hip_bf16.h>
#include <cstdint>

// Problem constants
#define BB  8
#define CH  64
#define TT  4096
#define KNN 9

// Workspace layout (float elements)
// qhat [B][C][T] ; khat [B][C][T] ; u [B][9][T][C] ; cwp [9][64][64] ; idx [B][T][9] (int)
constexpr size_t OFF_QHAT = 0;
constexpr size_t OFF_KHAT = (size_t)BB * CH * TT;                 // 2,097,152
constexpr size_t OFF_U    = OFF_KHAT + (size_t)BB * CH * TT;      // 4,194,304
constexpr size_t OFF_CWP  = OFF_U + (size_t)BB * KNN * TT * CH;   // 23,068,672
constexpr size_t OFF_IDX  = OFF_CWP + (size_t)KNN * CH * CH;      // 23,105,536
// total ~93.6 MB of ws

// ---------------------------------------------------------------------------
// K0: repack conv_w[o][cc*9+kk] -> cwp[kk][cc][o]  (coalesced writes)
// ---------------------------------------------------------------------------
__global__ void repack_cw_kernel(const float* __restrict__ cw, float* __restrict__ cwp) {
    int e = blockIdx.x * blockDim.x + threadIdx.x;
    if (e >= KNN * CH * CH) return;
    int o  = e & 63;
    int cc = (e >> 6) & 63;
    int kk = e >> 12;
    cwp[e] = cw[o * (CH * KNN) + cc * KNN + kk];
}

// ---------------------------------------------------------------------------
// K1: QKV projection + L2 normalize (channel dim) + u-projection
//     grid 512 = (b in 8) x (t-tile of 64 in 64), block 256
// ---------------------------------------------------------------------------
__global__ __launch_bounds__(256) void qkvu_kernel(
        const float* __restrict__ x,
        const float* __restrict__ Wq, const float* __restrict__ Wk, const float* __restrict__ Wv,
        const float* __restrict__ cwp,
        float* __restrict__ qhat, float* __restrict__ khat, float* __restrict__ u) {
    __shared__ __align__(16) float xs[CH * 64];   // xs[c][t]
    __shared__ __align__(16) float vs[CH * 64];   // vs[c][t]
    __shared__ __align__(16) float wl[CH * 64];   // wl[cc][o] (per kk)
    __shared__ float pq[4 * 64], pk[4 * 64];

    const int b   = blockIdx.x >> 6;
    const int tb  = blockIdx.x & 63;
    const int tid = threadIdx.x;

    // stage x tile [c][t], coalesced
    const float* xb = x + ((size_t)b * CH) * TT + tb * 64;
    #pragma unroll
    for (int m = 0; m < 16; ++m) {
        int l = tid + 256 * m;
        xs[l] = xb[(size_t)(l >> 6) * TT + (l & 63)];
    }
    __syncthreads();

    const int t = tid & 63;
    // wave index (uniform; readfirstlane tells the compiler -> scalar weight loads)
    const int g = __builtin_amdgcn_readfirstlane(tid >> 6);
    const int d0 = g * 16;

    float qa[16], ka[16], va[16];
    #pragma unroll
    for (int dd = 0; dd < 16; ++dd) { qa[dd] = 0.f; ka[dd] = 0.f; va[dd] = 0.f; }

    #pragma unroll 4
    for (int c = 0; c < CH; ++c) {
        float xv = xs[c * 64 + t];
        #pragma unroll
        for (int dd = 0; dd < 16; ++dd) {
            qa[dd] = fmaf(Wq[(d0 + dd) * CH + c], xv, qa[dd]);
            ka[dd] = fmaf(Wk[(d0 + dd) * CH + c], xv, ka[dd]);
            va[dd] = fmaf(Wv[(d0 + dd) * CH + c], xv, va[dd]);
        }
    }

    // partial squared norms over this wave's 16 channels
    float sq = 0.f, sk = 0.f;
    #pragma unroll
    for (int dd = 0; dd < 16; ++dd) { sq = fmaf(qa[dd], qa[dd], sq); sk = fmaf(ka[dd], ka[dd], sk); }
    pq[g * 64 + t] = sq;
    pk[g * 64 + t] = sk;
    __syncthreads();

    const float nq = sqrtf(pq[t] + pq[64 + t] + pq[128 + t] + pq[192 + t]);
    const float nk = sqrtf(pk[t] + pk[64 + t] + pk[128 + t] + pk[192 + t]);
    const float isq = 1.0f / fmaxf(nq, 1e-12f);
    const float isk = 1.0f / fmaxf(nk, 1e-12f);

    #pragma unroll
    for (int dd = 0; dd < 16; ++dd) {
        size_t go = ((size_t)b * CH + (d0 + dd)) * TT + tb * 64 + t;
        qhat[go] = qa[dd] * isq;
        khat[go] = ka[dd] * isk;
        vs[(d0 + dd) * 64 + t] = va[dd];
    }
    __syncthreads();

    // u projection: u[b][kk][t][o] = sum_cc cwp[kk][cc][o] * vs[cc][t]
    const int to = tid & 15;   // o group (4 o's)
    const int tt = tid >> 4;   // t group (4 t's)
    for (int kk = 0; kk < KNN; ++kk) {
        #pragma unroll
        for (int m = 0; m < 16; ++m) {
            int l = tid + 256 * m;
            wl[l] = cwp[kk * (CH * CH) + l];
        }
        __syncthreads();
        float acc[4][4];
        #pragma unroll
        for (int i = 0; i < 4; ++i)
            #pragma unroll
            for (int j = 0; j < 4; ++j) acc[i][j] = 0.f;

        #pragma unroll 8
        for (int cc = 0; cc < CH; ++cc) {
            float4 wv = *(const float4*)&wl[cc * 64 + 4 * to];
            float4 vv = *(const float4*)&vs[cc * 64 + 4 * tt];
            const float wj[4] = {wv.x, wv.y, wv.z, wv.w};
            const float vi[4] = {vv.x, vv.y, vv.z, vv.w};
            #pragma unroll
            for (int i = 0; i < 4; ++i)
                #pragma unroll
                for (int j = 0; j < 4; ++j) acc[i][j] = fmaf(vi[i], wj[j], acc[i][j]);
        }
        #pragma unroll
        for (int i = 0; i < 4; ++i) {
            size_t row = (size_t)(b * KNN + kk) * TT + tb * 64 + 4 * tt + i;
            *(float4*)&u[row * CH + 4 * to] = make_float4(acc[i][0], acc[i][1], acc[i][2], acc[i][3]);
        }
        __syncthreads();
    }
}

// ---------------------------------------------------------------------------
// K2: fused sim GEMM (fp32) + per-row streaming top-9
//     grid 512 = (b in 8) x (i-block of 64 in 64), block 128 (2 waves)
// ---------------------------------------------------------------------------
__global__ __launch_bounds__(128) void sim_topk_kernel(
        const float* __restrict__ qhat, const float* __restrict__ khat,
        int* __restrict__ idxout) {
    __shared__ __align__(16) float kt[CH * 64];   // kt[c][i]
    __shared__ __align__(16) float qt[CH * 64];   // qt[c][j]
    __shared__ float st[64 * 65];                 // sim tile, stride 65
    __shared__ float cv[64 * 18];
    __shared__ int   ci[64 * 18];

    const int b   = blockIdx.x >> 6;
    const int ib  = blockIdx.x & 63;
    const int tid = threadIdx.x;

    // stage kt once (rows of this i-block)
    const float* kb = khat + (size_t)b * CH * TT + ib * 64;
    #pragma unroll
    for (int m = 0; m < 32; ++m) {
        int l = tid + 128 * m;
        kt[l] = kb[(size_t)(l >> 6) * TT + (l & 63)];
    }

    const int ti = tid >> 3;   // 0..15, owns i = ti + 16*rr (strided for bank spread)
    const int tj = tid & 7;    // owns j = 8*tj + jj
    const int r  = tid >> 1;   // scan row
    const int h  = tid & 1;    // scan half

    float s[9]; int si[9];
    #pragma unroll
    for (int k = 0; k < 9; ++k) { s[k] = -3.402823466e38f; si[k] = 0; }

    const float* qb = qhat + (size_t)b * CH * TT;

    for (int jt = 0; jt < 64; ++jt) {
        // stage qt tile
        #pragma unroll
        for (int m = 0; m < 32; ++m) {
            int l = tid + 128 * m;
            qt[l] = qb[(size_t)(l >> 6) * TT + jt * 64 + (l & 63)];
        }
        __syncthreads();

        float acc[4][8];
        #pragma unroll
        for (int i = 0; i < 4; ++i)
            #pragma unroll
            for (int j = 0; j < 8; ++j) acc[i][j] = 0.f;

        #pragma unroll 8
        for (int c = 0; c < CH; ++c) {
            float k0 = kt[c * 64 + ti];
            float k1 = kt[c * 64 + ti + 16];
            float k2 = kt[c * 64 + ti + 32];
            float k3 = kt[c * 64 + ti + 48];
            float4 qa = *(const float4*)&qt[c * 64 + 8 * tj];
            float4 qc = *(const float4*)&qt[c * 64 + 8 * tj + 4];
            const float qv[8] = {qa.x, qa.y, qa.z, qa.w, qc.x, qc.y, qc.z, qc.w};
            #pragma unroll
            for (int j = 0; j < 8; ++j) {
                acc[0][j] = fmaf(k0, qv[j], acc[0][j]);
                acc[1][j] = fmaf(k1, qv[j], acc[1][j]);
                acc[2][j] = fmaf(k2, qv[j], acc[2][j]);
                acc[3][j] = fmaf(k3, qv[j], acc[3][j]);
            }
        }
        // dump sim tile to LDS (2-way banks thanks to strided i + stride 65)
        #pragma unroll
        for (int rr = 0; rr < 4; ++rr)
            #pragma unroll
            for (int jj = 0; jj < 8; ++jj)
                st[(ti + 16 * rr) * 65 + 8 * tj + jj] = acc[rr][jj];
        __syncthreads();

        // streaming top-9 scan: thread owns row r, half h
        const int jbase = jt * 64;
        #pragma unroll 2
        for (int ss = 0; ss < 32; ++ss) {
            int col = h * 32 + ((ss + 2 * r) & 31);   // rotation -> (3r+ss) banks
            float vv = st[r * 65 + col];
            if (__any(vv > s[0])) {
                const bool a0 = vv > s[0];
                const float w = a0 ? vv : s[0];       // no-op insert for !a0 lanes
                const int  wi = jbase + col;
                bool cnd[9];
                cnd[0] = a0;
                #pragma unroll
                for (int k = 1; k < 9; ++k) cnd[k] = w > s[k];
                #pragma unroll
                for (int k = 0; k < 8; ++k) {
                    s[k]  = cnd[k + 1] ? s[k + 1]  : (cnd[k] ? w  : s[k]);
                    si[k] = cnd[k + 1] ? si[k + 1] : (cnd[k] ? wi : si[k]);
                }
                s[8]  = cnd[8] ? w  : s[8];
                si[8] = cnd[8] ? wi : si[8];
            }
        }
        __syncthreads();
    }

    // merge the two half-lists per row; emit indices in value-desc order
    #pragma unroll
    for (int k = 0; k < 9; ++k) {
        cv[r * 18 + h * 9 + k] = s[k];
        ci[r * 18 + h * 9 + k] = si[k];
    }
    __syncthreads();
    if (h == 0) {
        int pa = 8, pb = 8;
        int* orow = idxout + ((size_t)b * TT + ib * 64 + r) * KNN;
        for (int m = 0; m < KNN; ++m) {
            float av = (pa >= 0) ? cv[r * 18 + pa]     : -3.402823466e38f;
            int   ai = (pa >= 0) ? ci[r * 18 + pa]     : 0x7fffffff;
            float bv = (pb >= 0) ? cv[r * 18 + 9 + pb] : -3.402823466e38f;
            int   bi = (pb >= 0) ? ci[r * 18 + 9 + pb] : 0x7fffffff;
            bool takeA = (av > bv) || (av == bv && ai < bi);
            orow[m] = takeA ? ai : bi;
            if (takeA) --pa; else --pb;
        }
    }
}

// ---------------------------------------------------------------------------
// K3: out[b][o][t] = conv_b[o] + sum_kk u[b][kk][idx[b][t][kk]][o]
//     grid 512 = (b in 8) x (t-tile 64 in 64), block 64
// ---------------------------------------------------------------------------
__global__ __launch_bounds__(64) void gather_conv_kernel(
        const float* __restrict__ u, const int* __restrict__ idxin,
        const float* __restrict__ conv_b, float* __restrict__ out) {
    __shared__ float cb[CH];
    const int b    = blockIdx.x >> 6;
    const int tb   = blockIdx.x & 63;
    const int lane = threadIdx.x;
    cb[lane] = conv_b[lane];
    __syncthreads();

    const int i = tb * 64 + lane;
    const int* ip = idxin + ((size_t)b * TT + i) * KNN;

    float acc[CH];
    #pragma unroll
    for (int o = 0; o < CH; ++o) acc[o] = cb[o];

    #pragma unroll
    for (int kk = 0; kk < KNN; ++kk) {
        int j = ip[kk];
        const float* up = u + ((size_t)(b * KNN + kk) * TT + j) * CH;
        #pragma unroll
        for (int o4 = 0; o4 < 16; ++o4) {
            float4 uv = *(const float4*)&up[o4 * 4];
            acc[o4 * 4 + 0] += uv.x;
            acc[o4 * 4 + 1] += uv.y;
            acc[o4 * 4 + 2] += uv.z;
            acc[o4 * 4 + 3] += uv.w;
        }
    }
    #pragma unroll
    for (int o = 0; o < CH; ++o)
        out[((size_t)b * CH + o) * TT + i] = acc[o];
}

// ---------------------------------------------------------------------------
extern "C" void kernel_launch(void* const* d_in, const int* in_sizes, int n_in,
                              void* d_out, int out_size, void* d_ws, size_t ws_size,
                              hipStream_t stream) {
    const float* x   = (const float*)d_in[0];
    const float* Wq  = (const float*)d_in[1];
    const float* Wk  = (const float*)d_in[2];
    const float* Wv  = (const float*)d_in[3];
    const float* cw  = (const float*)d_in[4];
    const float* cbp = (const float*)d_in[5];

    float* ws   = (float*)d_ws;
    float* qhat = ws + OFF_QHAT;
    float* khat = ws + OFF_KHAT;
    float* u    = ws + OFF_U;
    float* cwp  = ws + OFF_CWP;
    int*   idx  = (int*)(ws + OFF_IDX);
    float* out  = (float*)d_out;

    repack_cw_kernel<<<(KNN * CH * CH + 255) / 256, 256, 0, stream>>>(cw, cwp);
    qkvu_kernel<<<BB * 64, 256, 0, stream>>>(x, Wq, Wk, Wv, cwp, qhat, khat, u);
    sim_topk_kernel<<<BB * 64, 128, 0, stream>>>(qhat, khat, idx);
    gather_conv_kernel<<<BB * 64, 64, 0, stream>>>(u, idx, cbp, out);
}

// Round 2
// 534.401 us; speedup vs baseline: 1.2166x; 1.2166x over previous
//
#include <hip/hip_runtime.h>
#include <hip/hip_bf16.h>
#include <cstdint>

// Problem constants
#define BB  8
#define CH  64
#define TT  4096
#define KNN 9

#define NEG_INF (-3.402823466e38f)

// Workspace layout (float elements)
constexpr size_t OFF_QHAT = 0;                                    // [B][C][T]
constexpr size_t OFF_KHAT = (size_t)BB * CH * TT;                 //  2,097,152
constexpr size_t OFF_U    = OFF_KHAT + (size_t)BB * CH * TT;      //  4,194,304  u[B][9][T][C]
constexpr size_t OFF_CWP  = OFF_U + (size_t)BB * KNN * TT * CH;   // 23,068,672  cwp[9][64][64]
constexpr size_t OFF_PV   = OFF_CWP + (size_t)KNN * CH * CH;      // 23,105,536  pv[B][2][T][9]
constexpr size_t OFF_PI   = OFF_PV + (size_t)BB * 2 * TT * KNN;   // 23,695,360  pi[B][2][T][9]
constexpr size_t OFF_IDX  = OFF_PI + (size_t)BB * 2 * TT * KNN;   // 24,285,184  idx[B][T][9]
// end = 24,580,096 floats = 98.3 MB

// ---------------------------------------------------------------------------
// sorted-9 ascending insert (s[0]=9th best). Caller guarantees w > s[0].
// values via v_med3_f32 (9 ops), indices via cmp+cndmask.
// ---------------------------------------------------------------------------
__device__ __forceinline__ void insert9(float w, int wi, float s[9], int si[9]) {
    bool c[9];
    c[0] = true;
    #pragma unroll
    for (int k = 1; k < 9; ++k) c[k] = w > s[k];
    #pragma unroll
    for (int k = 0; k < 8; ++k) si[k] = c[k + 1] ? si[k + 1] : (c[k] ? wi : si[k]);
    si[8] = c[8] ? wi : si[8];
    #pragma unroll
    for (int k = 0; k < 8; ++k) s[k] = __builtin_amdgcn_fmed3f(s[k], s[k + 1], w);
    s[8] = fmaxf(s[8], w);
}

// scan a batch of 8 candidates (row-slice of acc) into list (s,si).
// Batch-argmax prefilter: whole-wave while loop, each firing lane inserts its
// current batch max, masks it, recomputes. Strict '>' keeps smallest index on
// ties (matches stable lax.top_k).
__device__ __forceinline__ void scan8(float a[8], int jcol0, float s[9], int si[9]) {
    float m = a[0]; int mj = 0;
    #pragma unroll
    for (int j = 1; j < 8; ++j) { bool g = a[j] > m; m = g ? a[j] : m; mj = g ? j : mj; }
    while (__any(m > s[0])) {
        if (m > s[0]) {
            insert9(m, jcol0 + mj, s, si);
            #pragma unroll
            for (int j = 0; j < 8; ++j) a[j] = (j == mj) ? NEG_INF : a[j];
        }
        m = a[0]; mj = 0;
        #pragma unroll
        for (int j = 1; j < 8; ++j) { bool g = a[j] > m; m = g ? a[j] : m; mj = g ? j : mj; }
    }
}

// merge the 8 per-lane lists of one row (lanes share ti, i.e. 8 consecutive
// lanes) via shfl_xor; winner's owner pops and writes (value desc, idx-asc on
// ties) to pv/pi.
__device__ __forceinline__ void merge8(float s[9], int si[9], float* pvrow, int* pirow) {
    #pragma unroll 1
    for (int m = 0; m < 9; ++m) {
        float hv = s[8]; int hi = si[8];
        #pragma unroll
        for (int d = 1; d < 8; d <<= 1) {
            float ov = __shfl_xor(hv, d);
            int   oi = __shfl_xor(hi, d);
            bool take = (ov > hv) || (ov == hv && oi < hi);
            hv = take ? ov : hv; hi = take ? oi : hi;
        }
        if (s[8] == hv && si[8] == hi) {   // unique owner (col indices unique)
            pvrow[m] = hv; pirow[m] = hi;
            #pragma unroll
            for (int k = 8; k > 0; --k) { s[k] = s[k - 1]; si[k] = si[k - 1]; }
            s[0] = NEG_INF; si[0] = -1;
        }
    }
}

// ---------------------------------------------------------------------------
// K0: repack conv_w[o][cc*9+kk] -> cwp[kk][cc][o]
// ---------------------------------------------------------------------------
__global__ void repack_cw_kernel(const float* __restrict__ cw, float* __restrict__ cwp) {
    int e = blockIdx.x * blockDim.x + threadIdx.x;
    if (e >= KNN * CH * CH) return;
    int o  = e & 63;
    int cc = (e >> 6) & 63;
    int kk = e >> 12;
    cwp[e] = cw[o * (CH * KNN) + cc * KNN + kk];
}

// ---------------------------------------------------------------------------
// K1: QKV projection + L2 normalize + u-projection (unchanged, passing)
// ---------------------------------------------------------------------------
__global__ __launch_bounds__(256) void qkvu_kernel(
        const float* __restrict__ x,
        const float* __restrict__ Wq, const float* __restrict__ Wk, const float* __restrict__ Wv,
        const float* __restrict__ cwp,
        float* __restrict__ qhat, float* __restrict__ khat, float* __restrict__ u) {
    __shared__ __align__(16) float xs[CH * 64];
    __shared__ __align__(16) float vs[CH * 64];
    __shared__ __align__(16) float wl[CH * 64];
    __shared__ float pq[4 * 64], pk[4 * 64];

    const int b   = blockIdx.x >> 6;
    const int tb  = blockIdx.x & 63;
    const int tid = threadIdx.x;

    const float* xb = x + ((size_t)b * CH) * TT + tb * 64;
    #pragma unroll
    for (int m = 0; m < 16; ++m) {
        int l = tid + 256 * m;
        xs[l] = xb[(size_t)(l >> 6) * TT + (l & 63)];
    }
    __syncthreads();

    const int t = tid & 63;
    const int g = __builtin_amdgcn_readfirstlane(tid >> 6);
    const int d0 = g * 16;

    float qa[16], ka[16], va[16];
    #pragma unroll
    for (int dd = 0; dd < 16; ++dd) { qa[dd] = 0.f; ka[dd] = 0.f; va[dd] = 0.f; }

    #pragma unroll 4
    for (int c = 0; c < CH; ++c) {
        float xv = xs[c * 64 + t];
        #pragma unroll
        for (int dd = 0; dd < 16; ++dd) {
            qa[dd] = fmaf(Wq[(d0 + dd) * CH + c], xv, qa[dd]);
            ka[dd] = fmaf(Wk[(d0 + dd) * CH + c], xv, ka[dd]);
            va[dd] = fmaf(Wv[(d0 + dd) * CH + c], xv, va[dd]);
        }
    }

    float sq = 0.f, sk = 0.f;
    #pragma unroll
    for (int dd = 0; dd < 16; ++dd) { sq = fmaf(qa[dd], qa[dd], sq); sk = fmaf(ka[dd], ka[dd], sk); }
    pq[g * 64 + t] = sq;
    pk[g * 64 + t] = sk;
    __syncthreads();

    const float nq = sqrtf(pq[t] + pq[64 + t] + pq[128 + t] + pq[192 + t]);
    const float nk = sqrtf(pk[t] + pk[64 + t] + pk[128 + t] + pk[192 + t]);
    const float isq = 1.0f / fmaxf(nq, 1e-12f);
    const float isk = 1.0f / fmaxf(nk, 1e-12f);

    #pragma unroll
    for (int dd = 0; dd < 16; ++dd) {
        size_t go = ((size_t)b * CH + (d0 + dd)) * TT + tb * 64 + t;
        qhat[go] = qa[dd] * isq;
        khat[go] = ka[dd] * isk;
        vs[(d0 + dd) * 64 + t] = va[dd];
    }
    __syncthreads();

    const int to = tid & 15;
    const int tt = tid >> 4;
    for (int kk = 0; kk < KNN; ++kk) {
        #pragma unroll
        for (int m = 0; m < 16; ++m) {
            int l = tid + 256 * m;
            wl[l] = cwp[kk * (CH * CH) + l];
        }
        __syncthreads();
        float acc[4][4];
        #pragma unroll
        for (int i = 0; i < 4; ++i)
            #pragma unroll
            for (int j = 0; j < 4; ++j) acc[i][j] = 0.f;

        #pragma unroll 8
        for (int cc = 0; cc < CH; ++cc) {
            float4 wv = *(const float4*)&wl[cc * 64 + 4 * to];
            float4 vv = *(const float4*)&vs[cc * 64 + 4 * tt];
            const float wj[4] = {wv.x, wv.y, wv.z, wv.w};
            const float vi[4] = {vv.x, vv.y, vv.z, vv.w};
            #pragma unroll
            for (int i = 0; i < 4; ++i)
                #pragma unroll
                for (int j = 0; j < 4; ++j) acc[i][j] = fmaf(vi[i], wj[j], acc[i][j]);
        }
        #pragma unroll
        for (int i = 0; i < 4; ++i) {
            size_t row = (size_t)(b * KNN + kk) * TT + tb * 64 + 4 * tt + i;
            *(float4*)&u[row * CH + 4 * to] = make_float4(acc[i][0], acc[i][1], acc[i][2], acc[i][3]);
        }
        __syncthreads();
    }
}

// ---------------------------------------------------------------------------
// K2: fused sim GEMM (fp32) + register-resident streaming top-9
//     grid 1024 = b(8, low bits -> XCD swizzle) x ib(64) x jslice(2)
//     block 256 (4 waves). LDS = kt+qt = 32 KiB exactly.
//     Thread: rows {2ti,2ti+1}, cols {8tj..8tj+7}; 2 register lists of 9.
// ---------------------------------------------------------------------------
__global__ __launch_bounds__(256, 4) void sim_topk_kernel(
        const float* __restrict__ qhat, const float* __restrict__ khat,
        float* __restrict__ pv, int* __restrict__ pi) {
    __shared__ __align__(16) float kt[CH * 64];   // kt[c][i]
    __shared__ __align__(16) float qt[CH * 64];   // qt[c][j]

    const int b   = blockIdx.x & 7;
    const int ib  = (blockIdx.x >> 3) & 63;
    const int js  = blockIdx.x >> 9;              // 0..1
    const int tid = threadIdx.x;

    // stage k-tile (rows of this i-block), coalesced
    const float* kb = khat + ((size_t)b * CH) * TT + ib * 64;
    #pragma unroll
    for (int m = 0; m < 16; ++m) {
        int l = tid + 256 * m;
        kt[l] = kb[(size_t)(l >> 6) * TT + (l & 63)];
    }

    const int ti = tid >> 3;   // 0..31 -> rows 2ti, 2ti+1
    const int tj = tid & 7;    // cols 8tj..8tj+7

    float s0[9], s1[9]; int i0[9], i1[9];
    #pragma unroll
    for (int k = 0; k < 9; ++k) { s0[k] = NEG_INF; s1[k] = NEG_INF; i0[k] = 0; i1[k] = 0; }

    const float* qb = qhat + ((size_t)b * CH) * TT + js * 2048;

    for (int jt = 0; jt < 32; ++jt) {
        #pragma unroll
        for (int m = 0; m < 16; ++m) {
            int l = tid + 256 * m;
            qt[l] = qb[(size_t)(l >> 6) * TT + jt * 64 + (l & 63)];
        }
        __syncthreads();

        float a0[8], a1[8];
        #pragma unroll
        for (int j = 0; j < 8; ++j) { a0[j] = 0.f; a1[j] = 0.f; }

        #pragma unroll 8
        for (int c = 0; c < CH; ++c) {
            float2 kv = *(const float2*)&kt[c * 64 + 2 * ti];
            float4 qA = *(const float4*)&qt[c * 64 + 8 * tj];
            float4 qB = *(const float4*)&qt[c * 64 + 8 * tj + 4];
            const float qv[8] = {qA.x, qA.y, qA.z, qA.w, qB.x, qB.y, qB.z, qB.w};
            #pragma unroll
            for (int j = 0; j < 8; ++j) {
                a0[j] = fmaf(kv.x, qv[j], a0[j]);
                a1[j] = fmaf(kv.y, qv[j], a1[j]);
            }
        }
        __syncthreads();   // qt consumed; scan below is register-only

        const int j0 = js * 2048 + jt * 64 + 8 * tj;
        scan8(a0, j0, s0, i0);
        scan8(a1, j0, s1, i1);
    }

    // per-row merge of the 8 per-lane lists (shfl over lanes sharing ti)
    const int gi = ib * 64 + 2 * ti;
    float* pv0 = pv + (((size_t)(b * 2 + js)) * TT + gi) * KNN;
    int*   pi0 = pi + (((size_t)(b * 2 + js)) * TT + gi) * KNN;
    merge8(s0, i0, pv0, pi0);
    merge8(s1, i1, pv0 + KNN, pi0 + KNN);
}

// ---------------------------------------------------------------------------
// K2b: merge the 2 j-slice partial lists per row -> final idx[b][t][9]
// ---------------------------------------------------------------------------
__global__ __launch_bounds__(256) void merge_slices_kernel(
        const float* __restrict__ pv, const int* __restrict__ pi,
        int* __restrict__ idxout) {
    int r = blockIdx.x * blockDim.x + threadIdx.x;
    if (r >= BB * TT) return;
    int b = r >> 12, i = r & (TT - 1);

    float s[9]; int si[9];
    #pragma unroll
    for (int k = 0; k < 9; ++k) { s[k] = NEG_INF; si[k] = 0; }

    #pragma unroll
    for (int js = 0; js < 2; ++js) {
        const float* pvr = pv + (((size_t)(b * 2 + js)) * TT + i) * KNN;
        const int*   pir = pi + (((size_t)(b * 2 + js)) * TT + i) * KNN;
        #pragma unroll
        for (int m = 0; m < 9; ++m) {
            float w = pvr[m]; int wi = pir[m];
            if (w > s[0]) insert9(w, wi, s, si);
        }
    }
    int* orow = idxout + ((size_t)b * TT + i) * KNN;
    #pragma unroll
    for (int m = 0; m < 9; ++m) orow[m] = si[8 - m];
}

// ---------------------------------------------------------------------------
// K3: out[b][o][t] = conv_b[o] + sum_kk u[b][kk][idx[b][t][kk]][o]
//     grid 512 = b(8, XCD swizzle) x t-tile(64); block 256 = 4 o-groups x 64 t
// ---------------------------------------------------------------------------
__global__ __launch_bounds__(256) void gather_conv_kernel(
        const float* __restrict__ u, const int* __restrict__ idxin,
        const float* __restrict__ conv_b, float* __restrict__ out) {
    __shared__ int   sidx[64 * KNN];
    __shared__ float cb[CH];
    const int b   = blockIdx.x & 7;
    const int tb  = blockIdx.x >> 3;
    const int tid = threadIdx.x;

    if (tid < CH) cb[tid] = conv_b[tid];
    const int* ig = idxin + ((size_t)b * TT + tb * 64) * KNN;
    for (int l = tid; l < 64 * KNN; l += 256) sidx[l] = ig[l];
    __syncthreads();

    const int tl = tid & 63;
    const int og = tid >> 6;       // 0..3
    const int o0 = og * 16;

    float acc[16];
    #pragma unroll
    for (int q = 0; q < 16; ++q) acc[q] = cb[o0 + q];

    #pragma unroll
    for (int kk = 0; kk < KNN; ++kk) {
        int j = sidx[tl * KNN + kk];
        const float* up = u + (((size_t)(b * KNN + kk)) * TT + j) * CH + o0;
        #pragma unroll
        for (int q4 = 0; q4 < 4; ++q4) {
            float4 uv = *(const float4*)&up[q4 * 4];
            acc[q4 * 4 + 0] += uv.x;
            acc[q4 * 4 + 1] += uv.y;
            acc[q4 * 4 + 2] += uv.z;
            acc[q4 * 4 + 3] += uv.w;
        }
    }
    const int t = tb * 64 + tl;
    #pragma unroll
    for (int q = 0; q < 16; ++q)
        out[((size_t)b * CH + o0 + q) * TT + t] = acc[q];
}

// ---------------------------------------------------------------------------
extern "C" void kernel_launch(void* const* d_in, const int* in_sizes, int n_in,
                              void* d_out, int out_size, void* d_ws, size_t ws_size,
                              hipStream_t stream) {
    const float* x   = (const float*)d_in[0];
    const float* Wq  = (const float*)d_in[1];
    const float* Wk  = (const float*)d_in[2];
    const float* Wv  = (const float*)d_in[3];
    const float* cw  = (const float*)d_in[4];
    const float* cbp = (const float*)d_in[5];

    float* ws   = (float*)d_ws;
    float* qhat = ws + OFF_QHAT;
    float* khat = ws + OFF_KHAT;
    float* u    = ws + OFF_U;
    float* cwp  = ws + OFF_CWP;
    float* pv   = ws + OFF_PV;
    int*   pi   = (int*)(ws + OFF_PI);
    int*   idx  = (int*)(ws + OFF_IDX);
    float* out  = (float*)d_out;

    repack_cw_kernel<<<(KNN * CH * CH + 255) / 256, 256, 0, stream>>>(cw, cwp);
    qkvu_kernel<<<BB * 64, 256, 0, stream>>>(x, Wq, Wk, Wv, cwp, qhat, khat, u);
    sim_topk_kernel<<<BB * 64 * 2, 256, 0, stream>>>(qhat, khat, pv, pi);
    merge_slices_kernel<<<(BB * TT + 255) / 256, 256, 0, stream>>>(pv, pi, idx);
    gather_conv_kernel<<<BB * 64, 256, 0, stream>>>(u, idx, cbp, out);
}